// Round 9
// baseline (245.052 us; speedup 1.0000x reference)
//
#include <hip/hip_runtime.h>

#define DD 128          // feature dim
#define KC 32           // k-chunk in gemm
#define MT 64           // rows per block in gemm
#define ELLC 128        // ELL row capacity (deg ~ Poisson(32); max over 20K nodes ~65)
#define NBMAX 320       // max dst-buckets (64 nodes each)
#define ACAP 2304       // bucket capacity: mean 2045, sigma ~45 -> +5.7 sigma
#define AEPW 4096       // edges per phase-A workgroup

__device__ __forceinline__ unsigned f2bf_rne(float f) {
    unsigned u = __float_as_uint(f);
    u += 0x7fffu + ((u >> 16) & 1u);
    return u >> 16;
}

// ---------------- GEMM body ----------------
// xt = x @ W.T + b (fp32, possibly IN-PLACE on x: each block reads only its own
// 64 rows and writes them in the epilogue after all k-chunks are consumed),
// plus packed-bf16 copy xtb. 256 threads, 64x128 tile.
__device__ __forceinline__ void gemm_body(float Xs[KC][MT + 4], float Ws[KC][DD + 4],
                                          const float* x,
                                          const float* __restrict__ W,
                                          const float* __restrict__ b,
                                          float* xt,
                                          unsigned* __restrict__ xtb, int M, int blk) {
    const int tid  = threadIdx.x;       // 0..255
    const int cg   = tid & 15;          // cols cg*8 .. cg*8+7
    const int rg   = tid >> 4;          // rows rg*4 .. rg*4+3
    const int row0 = blk * MT;

    float acc[4][8];
#pragma unroll
    for (int i = 0; i < 4; ++i)
#pragma unroll
        for (int j = 0; j < 8; ++j) acc[i][j] = 0.0f;

    for (int kc = 0; kc < DD; kc += KC) {
#pragma unroll
        for (int it = 0; it < 2; ++it) {
            int idx = tid + it * 256;   // 0..511
            int r = idx >> 3, kq = idx & 7;
            int gr = row0 + r;
            float4 v = make_float4(0.f, 0.f, 0.f, 0.f);
            if (gr < M) v = *(const float4*)&x[gr * DD + kc + kq * 4];
            Xs[kq * 4 + 0][r] = v.x; Xs[kq * 4 + 1][r] = v.y;
            Xs[kq * 4 + 2][r] = v.z; Xs[kq * 4 + 3][r] = v.w;
        }
#pragma unroll
        for (int it = 0; it < 4; ++it) {
            int idx = tid + it * 256;   // 0..1023
            int o = idx >> 3, kq = idx & 7;
            float4 v = *(const float4*)&W[o * DD + kc + kq * 4];
            Ws[kq * 4 + 0][o] = v.x; Ws[kq * 4 + 1][o] = v.y;
            Ws[kq * 4 + 2][o] = v.z; Ws[kq * 4 + 3][o] = v.w;
        }
        __syncthreads();

#pragma unroll 8
        for (int k = 0; k < KC; ++k) {
            float4 xv = *(const float4*)&Xs[k][rg * 4];
            float4 w0 = *(const float4*)&Ws[k][cg * 8];
            float4 w1 = *(const float4*)&Ws[k][cg * 8 + 4];
            float xr[4] = {xv.x, xv.y, xv.z, xv.w};
            float wc[8] = {w0.x, w0.y, w0.z, w0.w, w1.x, w1.y, w1.z, w1.w};
#pragma unroll
            for (int i = 0; i < 4; ++i)
#pragma unroll
                for (int j = 0; j < 8; ++j) acc[i][j] += xr[i] * wc[j];
        }
        __syncthreads();
    }

    float4 b0 = *(const float4*)&b[cg * 8];
    float4 b1 = *(const float4*)&b[cg * 8 + 4];
    float bb[8] = {b0.x, b0.y, b0.z, b0.w, b1.x, b1.y, b1.z, b1.w};
#pragma unroll
    for (int i = 0; i < 4; ++i) {
        int gr = row0 + rg * 4 + i;
        if (gr < M) {
            float v[8];
#pragma unroll
            for (int j = 0; j < 8; ++j) v[j] = acc[i][j] + bb[j];
            *(float4*)&xt[gr * DD + cg * 8]     = make_float4(v[0], v[1], v[2], v[3]);
            *(float4*)&xt[gr * DD + cg * 8 + 4] = make_float4(v[4], v[5], v[6], v[7]);
            uint4 p;
            p.x = f2bf_rne(v[0]) | (f2bf_rne(v[1]) << 16);
            p.y = f2bf_rne(v[2]) | (f2bf_rne(v[3]) << 16);
            p.z = f2bf_rne(v[4]) | (f2bf_rne(v[5]) << 16);
            p.w = f2bf_rne(v[6]) | (f2bf_rne(v[7]) << 16);
            *(uint4*)&xtb[gr * 64 + cg * 4] = p;
        }
    }
}

__global__ __launch_bounds__(256) void gemm_xwT(const float* x,
                                                const float* __restrict__ W,
                                                const float* __restrict__ b,
                                                float* xt,
                                                unsigned* __restrict__ xtb, int M) {
    __shared__ float Xs[KC][MT + 4];
    __shared__ float Ws[KC][DD + 4];
    gemm_body(Xs, Ws, x, W, b, xt, xtb, M, blockIdx.x);
}

// Fused: blocks [0,PA) = Phase-A edge binning (LDS histogram -> few global
// atomics -> semi-coalesced bucket-store writes); blocks [PA,PA+GB) = GEMM-1.
__global__ __launch_bounds__(256) void gemm1_plus_binA(const float* x,
                                                       const float* __restrict__ W,
                                                       const float* __restrict__ b,
                                                       float* xt,
                                                       unsigned* __restrict__ xtb, int M,
                                                       const int* __restrict__ src,
                                                       const int* __restrict__ dst,
                                                       int* __restrict__ bucket_count,
                                                       unsigned* __restrict__ bstore,
                                                       int E, int NB, int PA) {
    __shared__ float Xs[KC][MT + 4];
    __shared__ float Ws[KC][DD + 4];
    __shared__ int hist[NBMAX];
    __shared__ int basec[NBMAX];
    __shared__ int cur[NBMAX];

    if ((int)blockIdx.x >= PA) {
        gemm_body(Xs, Ws, x, W, b, xt, xtb, M, blockIdx.x - PA);
        return;
    }

    const int tid = threadIdx.x;
    for (int i = tid; i < NB; i += 256) hist[i] = 0;
    __syncthreads();

    // load 16 edges/thread (4 rounds of coalesced int4)
    int dv[16], sv[16];
    const int ebase = blockIdx.x * AEPW;
#pragma unroll
    for (int r = 0; r < 4; ++r) {
        int e = ebase + r * 1024 + tid * 4;
        if (e + 4 <= E) {
            int4 d4 = *(const int4*)&dst[e];
            int4 s4 = *(const int4*)&src[e];
            dv[r*4+0] = d4.x; dv[r*4+1] = d4.y; dv[r*4+2] = d4.z; dv[r*4+3] = d4.w;
            sv[r*4+0] = s4.x; sv[r*4+1] = s4.y; sv[r*4+2] = s4.z; sv[r*4+3] = s4.w;
        } else {
#pragma unroll
            for (int q = 0; q < 4; ++q) {
                int ee = e + q;
                if (ee < E) { dv[r*4+q] = dst[ee]; sv[r*4+q] = src[ee]; }
                else        { dv[r*4+q] = -1;      sv[r*4+q] = 0; }
            }
        }
    }
#pragma unroll
    for (int i = 0; i < 16; ++i)
        if (dv[i] >= 0) atomicAdd(&hist[dv[i] >> 6], 1);
    __syncthreads();

    for (int bk = tid; bk < NB; bk += 256) {
        int h = hist[bk];
        basec[bk] = h ? atomicAdd(&bucket_count[bk], h) : 0;
        cur[bk] = 0;
    }
    __syncthreads();

#pragma unroll
    for (int i = 0; i < 16; ++i) {
        if (dv[i] >= 0) {
            int bk = dv[i] >> 6;
            int pos = basec[bk] + atomicAdd(&cur[bk], 1);
            if (pos < ACAP)
                bstore[bk * ACAP + pos] = ((unsigned)(dv[i] & 63) << 16) | (unsigned)sv[i];
        }
    }
}

// Phase B: one workgroup per bucket. Slot assignment via LDS atomics; colell
// writes stay in a private 16KB region (full-line writeback). Also emits deg.
__global__ __launch_bounds__(256) void ell_build(const unsigned* __restrict__ bstore,
                                                 const int* __restrict__ bucket_count,
                                                 unsigned short* __restrict__ colell,
                                                 int* __restrict__ deg, int N) {
    __shared__ int c64[64];
    const int bk = blockIdx.x;
    for (int i = threadIdx.x; i < 64; i += 256) c64[i] = 0;
    __syncthreads();
    int cnt = bucket_count[bk];
    if (cnt > ACAP) cnt = ACAP;
    for (int i = threadIdx.x; i < cnt; i += 256) {
        unsigned code = bstore[bk * ACAP + i];
        int local = (int)(code >> 16);
        int s     = (int)(code & 0xffffu);
        int p = atomicAdd(&c64[local], 1);
        if (p < ELLC)
            colell[((((bk << 6) + local)) << 7) + p] = (unsigned short)s;
    }
    __syncthreads();
    if (threadIdx.x < 64) {
        int node = (bk << 6) + threadIdx.x;
        if (node < N) deg[node] = c64[threadIdx.x];
    }
}

// ---------------- fused aggregate ----------------
// out[n,:] = relu( (sum_e bf16(xt[col[e],:])) / deg[n] ) + xt[n,:]
// One 64-lane wave per node. 8B gathers as nontemporal u64: lanes 0-31 carry
// edge 2t (features 4h..4h+3), lanes 32-63 edge 2t+1 -> 512 B / 2 edges per
// VMEM instr. FLIGHT-16 (typical 32-edge node = ONE vmcnt drain) + nt hint
// to keep the random gather out of L1's way.
__global__ void gcn_aggregate(const unsigned long long* __restrict__ xtb2, const float* xt,
                              const unsigned short* __restrict__ colell,
                              const int* __restrict__ deg,
                              float* out, int N) {
    const int gid  = blockIdx.x * blockDim.x + threadIdx.x;
    const int node = gid >> 6;
    const int lane = threadIdx.x & 63;
    if (node >= N) return;
    const int h    = lane & 31;     // feature-quad index: features 4h..4h+3
    const int half = lane >> 5;     // 0: even edges, 1: odd edges

    const unsigned long long* __restrict__ xl = xtb2 + h;
    const unsigned short* __restrict__ crow = colell + (node << 7);
    const int cnt = deg[node];      // wave-uniform

    float a0 = 0.f, a1 = 0.f, a2 = 0.f, a3 = 0.f;

    for (int base = 0; base < cnt; base += 64) {
        const int rem = cnt - base;
        const int c = rem < 64 ? rem : 64;
        const int myidx = (lane < c) ? (int)crow[base + lane] : 0;  // coalesced ushort
        const int pairs = c >> 1;
        int t = 0;
        for (; t + 16 <= pairs; t += 16) {   // flight of 16 instrs = 32 edges
            unsigned long long u[16];
#pragma unroll
            for (int q = 0; q < 16; ++q) {
                int s = __shfl(myidx, 2 * (t + q) + half, 64);
                u[q] = __builtin_nontemporal_load(&xl[s << 5]);
            }
#pragma unroll
            for (int q = 0; q < 16; ++q) {
                unsigned lo = (unsigned)u[q], hi = (unsigned)(u[q] >> 32);
                a0 += __uint_as_float(lo << 16);
                a1 += __uint_as_float(lo & 0xffff0000u);
                a2 += __uint_as_float(hi << 16);
                a3 += __uint_as_float(hi & 0xffff0000u);
            }
        }
        for (; t + 4 <= pairs; t += 4) {     // flight of 4
            unsigned long long u[4];
#pragma unroll
            for (int q = 0; q < 4; ++q) {
                int s = __shfl(myidx, 2 * (t + q) + half, 64);
                u[q] = __builtin_nontemporal_load(&xl[s << 5]);
            }
#pragma unroll
            for (int q = 0; q < 4; ++q) {
                unsigned lo = (unsigned)u[q], hi = (unsigned)(u[q] >> 32);
                a0 += __uint_as_float(lo << 16);
                a1 += __uint_as_float(lo & 0xffff0000u);
                a2 += __uint_as_float(hi << 16);
                a3 += __uint_as_float(hi & 0xffff0000u);
            }
        }
        for (; t < pairs; ++t) {
            int s = __shfl(myidx, 2 * t + half, 64);
            unsigned long long u = __builtin_nontemporal_load(&xl[s << 5]);
            unsigned lo = (unsigned)u, hi = (unsigned)(u >> 32);
            a0 += __uint_as_float(lo << 16);
            a1 += __uint_as_float(lo & 0xffff0000u);
            a2 += __uint_as_float(hi << 16);
            a3 += __uint_as_float(hi & 0xffff0000u);
        }
        if (c & 1) {                        // final unpaired edge: half 0 only
            int s = __shfl(myidx, c - 1, 64);
            if (half == 0) {
                unsigned long long u = __builtin_nontemporal_load(&xl[s << 5]);
                unsigned lo = (unsigned)u, hi = (unsigned)(u >> 32);
                a0 += __uint_as_float(lo << 16);
                a1 += __uint_as_float(lo & 0xffff0000u);
                a2 += __uint_as_float(hi << 16);
                a3 += __uint_as_float(hi & 0xffff0000u);
            }
        }
    }

    // merge odd-edge stream into lanes 0-31
    a0 += __shfl_down(a0, 32, 64);
    a1 += __shfl_down(a1, 32, 64);
    a2 += __shfl_down(a2, 32, 64);
    a3 += __shfl_down(a3, 32, 64);

    if (half == 0) {
        const float di = (cnt > 0) ? (1.0f / (float)cnt) : 0.0f;
        float4 t4 = ((const float4*)xt)[node * 32 + h];
        float4 o;
        o.x = fmaxf(a0 * di, 0.f) + t4.x;
        o.y = fmaxf(a1 * di, 0.f) + t4.y;
        o.z = fmaxf(a2 * di, 0.f) + t4.z;
        o.w = fmaxf(a3 * di, 0.f) + t4.w;
        ((float4*)out)[node * 32 + h] = o;
    }
}

extern "C" void kernel_launch(void* const* d_in, const int* in_sizes, int n_in,
                              void* d_out, int out_size, void* d_ws, size_t ws_size,
                              hipStream_t stream) {
    const float* x  = (const float*)d_in[0];
    const int*   ei = (const int*)d_in[1];      // [2, E] int32
    const float* W1 = (const float*)d_in[2];
    const float* b1 = (const float*)d_in[3];
    const float* W2 = (const float*)d_in[4];
    const float* b2 = (const float*)d_in[5];
    const float* W3 = (const float*)d_in[6];
    const float* b3 = (const float*)d_in[7];

    const int N  = in_sizes[0] / DD;     // 20000
    const int E  = in_sizes[1] / 2;      // 640000
    const int ND = N * DD;               // 2,560,000

    const int* src = ei;
    const int* dst = ei + E;

    const int NB = (N + 63) >> 6;        // 313 buckets
    const int PA = (E + AEPW - 1) / AEPW;    // 157 phase-A blocks
    const int GB = (N + MT - 1) / MT;        // 313 gemm blocks
    const int AB = (N + 3) / 4;              // aggregate blocks (4 waves/block)

    // workspace layout (256B-aligned offsets) — ~13.2 MB total
    char* ws = (char*)d_ws;
    size_t off = 0;
    auto alloc = [&](size_t bytes) {
        void* p = ws + off;
        off += (bytes + 255) & ~(size_t)255;
        return p;
    };
    int*            bucket_count = (int*)alloc((size_t)NB * sizeof(int));
    unsigned*       bstore       = (unsigned*)alloc((size_t)NB * ACAP * sizeof(unsigned));
    unsigned short* colell       = (unsigned short*)alloc((size_t)NB * 64 * ELLC * sizeof(unsigned short));
    int*            deg          = (int*)alloc((size_t)N * sizeof(int));
    unsigned*       xtb          = (unsigned*)alloc((size_t)(ND / 2) * sizeof(unsigned));

    float* xbuf = (float*)d_out;  // fp32 xt lives in d_out (in-place per layer)

    hipMemsetAsync(bucket_count, 0, (size_t)NB * sizeof(int), stream);
    // K1: Phase-A binning + layer-1 GEMM (x -> xbuf fp32 + xtb bf16)
    gemm1_plus_binA<<<PA + GB, 256, 0, stream>>>(x, W1, b1, xbuf, xtb, N,
                                                 src, dst, bucket_count, bstore, E, NB, PA);
    // K2: Phase-B ELL build (LDS atomics, local writes) + deg
    ell_build<<<NB, 256, 0, stream>>>(bstore, bucket_count, colell, deg, N);

    gcn_aggregate<<<AB, 256, 0, stream>>>((const unsigned long long*)xtb, xbuf, colell, deg, xbuf, N);

    gemm_xwT<<<GB, 256, 0, stream>>>(xbuf, W2, b2, xbuf, xtb, N);
    gcn_aggregate<<<AB, 256, 0, stream>>>((const unsigned long long*)xtb, xbuf, colell, deg, xbuf, N);

    gemm_xwT<<<GB, 256, 0, stream>>>(xbuf, W3, b3, xbuf, xtb, N);
    gcn_aggregate<<<AB, 256, 0, stream>>>((const unsigned long long*)xtb, xbuf, colell, deg, xbuf, N);
}

// Round 10
// 214.851 us; speedup vs baseline: 1.1406x; 1.1406x over previous
//
#include <hip/hip_runtime.h>

#define DD 128          // feature dim
#define KC 32           // k-chunk in gemm
#define MT 64           // rows per block in gemm
#define ELLC 128        // ELL row capacity (deg ~ Poisson(32); max over 20K nodes ~65)
#define NBMAX 320       // max dst-buckets (64 nodes each)
#define ACAP 2304       // bucket capacity: mean 2045, sigma ~45 -> +5.7 sigma
#define AEPW 4096       // edges per phase-A workgroup

__device__ __forceinline__ unsigned f2bf_rne(float f) {
    unsigned u = __float_as_uint(f);
    u += 0x7fffu + ((u >> 16) & 1u);
    return u >> 16;
}

// ---------------- GEMM body ----------------
// xt = x @ W.T + b (fp32, possibly IN-PLACE on x: each block reads only its own
// 64 rows and writes them in the epilogue after all k-chunks are consumed),
// plus packed-bf16 copy xtb. 256 threads, 64x128 tile.
__device__ __forceinline__ void gemm_body(float Xs[KC][MT + 4], float Ws[KC][DD + 4],
                                          const float* x,
                                          const float* __restrict__ W,
                                          const float* __restrict__ b,
                                          float* xt,
                                          unsigned* __restrict__ xtb, int M, int blk) {
    const int tid  = threadIdx.x;       // 0..255
    const int cg   = tid & 15;          // cols cg*8 .. cg*8+7
    const int rg   = tid >> 4;          // rows rg*4 .. rg*4+3
    const int row0 = blk * MT;

    float acc[4][8];
#pragma unroll
    for (int i = 0; i < 4; ++i)
#pragma unroll
        for (int j = 0; j < 8; ++j) acc[i][j] = 0.0f;

    for (int kc = 0; kc < DD; kc += KC) {
#pragma unroll
        for (int it = 0; it < 2; ++it) {
            int idx = tid + it * 256;   // 0..511
            int r = idx >> 3, kq = idx & 7;
            int gr = row0 + r;
            float4 v = make_float4(0.f, 0.f, 0.f, 0.f);
            if (gr < M) v = *(const float4*)&x[gr * DD + kc + kq * 4];
            Xs[kq * 4 + 0][r] = v.x; Xs[kq * 4 + 1][r] = v.y;
            Xs[kq * 4 + 2][r] = v.z; Xs[kq * 4 + 3][r] = v.w;
        }
#pragma unroll
        for (int it = 0; it < 4; ++it) {
            int idx = tid + it * 256;   // 0..1023
            int o = idx >> 3, kq = idx & 7;
            float4 v = *(const float4*)&W[o * DD + kc + kq * 4];
            Ws[kq * 4 + 0][o] = v.x; Ws[kq * 4 + 1][o] = v.y;
            Ws[kq * 4 + 2][o] = v.z; Ws[kq * 4 + 3][o] = v.w;
        }
        __syncthreads();

#pragma unroll 8
        for (int k = 0; k < KC; ++k) {
            float4 xv = *(const float4*)&Xs[k][rg * 4];
            float4 w0 = *(const float4*)&Ws[k][cg * 8];
            float4 w1 = *(const float4*)&Ws[k][cg * 8 + 4];
            float xr[4] = {xv.x, xv.y, xv.z, xv.w};
            float wc[8] = {w0.x, w0.y, w0.z, w0.w, w1.x, w1.y, w1.z, w1.w};
#pragma unroll
            for (int i = 0; i < 4; ++i)
#pragma unroll
                for (int j = 0; j < 8; ++j) acc[i][j] += xr[i] * wc[j];
        }
        __syncthreads();
    }

    float4 b0 = *(const float4*)&b[cg * 8];
    float4 b1 = *(const float4*)&b[cg * 8 + 4];
    float bb[8] = {b0.x, b0.y, b0.z, b0.w, b1.x, b1.y, b1.z, b1.w};
#pragma unroll
    for (int i = 0; i < 4; ++i) {
        int gr = row0 + rg * 4 + i;
        if (gr < M) {
            float v[8];
#pragma unroll
            for (int j = 0; j < 8; ++j) v[j] = acc[i][j] + bb[j];
            *(float4*)&xt[gr * DD + cg * 8]     = make_float4(v[0], v[1], v[2], v[3]);
            *(float4*)&xt[gr * DD + cg * 8 + 4] = make_float4(v[4], v[5], v[6], v[7]);
            uint4 p;
            p.x = f2bf_rne(v[0]) | (f2bf_rne(v[1]) << 16);
            p.y = f2bf_rne(v[2]) | (f2bf_rne(v[3]) << 16);
            p.z = f2bf_rne(v[4]) | (f2bf_rne(v[5]) << 16);
            p.w = f2bf_rne(v[6]) | (f2bf_rne(v[7]) << 16);
            *(uint4*)&xtb[gr * 64 + cg * 4] = p;
        }
    }
}

__global__ __launch_bounds__(256) void gemm_xwT(const float* x,
                                                const float* __restrict__ W,
                                                const float* __restrict__ b,
                                                float* xt,
                                                unsigned* __restrict__ xtb, int M) {
    __shared__ float Xs[KC][MT + 4];
    __shared__ float Ws[KC][DD + 4];
    gemm_body(Xs, Ws, x, W, b, xt, xtb, M, blockIdx.x);
}

// Fused: blocks [0,PA) = Phase-A edge binning (LDS histogram -> few global
// atomics -> semi-coalesced bucket-store writes); blocks [PA,PA+GB) = GEMM-1.
__global__ __launch_bounds__(256) void gemm1_plus_binA(const float* x,
                                                       const float* __restrict__ W,
                                                       const float* __restrict__ b,
                                                       float* xt,
                                                       unsigned* __restrict__ xtb, int M,
                                                       const int* __restrict__ src,
                                                       const int* __restrict__ dst,
                                                       int* __restrict__ bucket_count,
                                                       unsigned* __restrict__ bstore,
                                                       int E, int NB, int PA) {
    __shared__ float Xs[KC][MT + 4];
    __shared__ float Ws[KC][DD + 4];
    __shared__ int hist[NBMAX];
    __shared__ int basec[NBMAX];
    __shared__ int cur[NBMAX];

    if ((int)blockIdx.x >= PA) {
        gemm_body(Xs, Ws, x, W, b, xt, xtb, M, blockIdx.x - PA);
        return;
    }

    const int tid = threadIdx.x;
    for (int i = tid; i < NB; i += 256) hist[i] = 0;
    __syncthreads();

    // load 16 edges/thread (4 rounds of coalesced int4)
    int dv[16], sv[16];
    const int ebase = blockIdx.x * AEPW;
#pragma unroll
    for (int r = 0; r < 4; ++r) {
        int e = ebase + r * 1024 + tid * 4;
        if (e + 4 <= E) {
            int4 d4 = *(const int4*)&dst[e];
            int4 s4 = *(const int4*)&src[e];
            dv[r*4+0] = d4.x; dv[r*4+1] = d4.y; dv[r*4+2] = d4.z; dv[r*4+3] = d4.w;
            sv[r*4+0] = s4.x; sv[r*4+1] = s4.y; sv[r*4+2] = s4.z; sv[r*4+3] = s4.w;
        } else {
#pragma unroll
            for (int q = 0; q < 4; ++q) {
                int ee = e + q;
                if (ee < E) { dv[r*4+q] = dst[ee]; sv[r*4+q] = src[ee]; }
                else        { dv[r*4+q] = -1;      sv[r*4+q] = 0; }
            }
        }
    }
#pragma unroll
    for (int i = 0; i < 16; ++i)
        if (dv[i] >= 0) atomicAdd(&hist[dv[i] >> 6], 1);
    __syncthreads();

    for (int bk = tid; bk < NB; bk += 256) {
        int h = hist[bk];
        basec[bk] = h ? atomicAdd(&bucket_count[bk], h) : 0;
        cur[bk] = 0;
    }
    __syncthreads();

#pragma unroll
    for (int i = 0; i < 16; ++i) {
        if (dv[i] >= 0) {
            int bk = dv[i] >> 6;
            int pos = basec[bk] + atomicAdd(&cur[bk], 1);
            if (pos < ACAP)
                bstore[bk * ACAP + pos] = ((unsigned)(dv[i] & 63) << 16) | (unsigned)sv[i];
        }
    }
}

// Phase B: one workgroup per bucket. Slot assignment via LDS atomics; colell
// writes stay in a private 16KB region (full-line writeback). Also emits deg.
__global__ __launch_bounds__(256) void ell_build(const unsigned* __restrict__ bstore,
                                                 const int* __restrict__ bucket_count,
                                                 unsigned short* __restrict__ colell,
                                                 int* __restrict__ deg, int N) {
    __shared__ int c64[64];
    const int bk = blockIdx.x;
    for (int i = threadIdx.x; i < 64; i += 256) c64[i] = 0;
    __syncthreads();
    int cnt = bucket_count[bk];
    if (cnt > ACAP) cnt = ACAP;
    for (int i = threadIdx.x; i < cnt; i += 256) {
        unsigned code = bstore[bk * ACAP + i];
        int local = (int)(code >> 16);
        int s     = (int)(code & 0xffffu);
        int p = atomicAdd(&c64[local], 1);
        if (p < ELLC)
            colell[((((bk << 6) + local)) << 7) + p] = (unsigned short)s;
    }
    __syncthreads();
    if (threadIdx.x < 64) {
        int node = (bk << 6) + threadIdx.x;
        if (node < N) deg[node] = c64[threadIdx.x];
    }
}

// ---------------- fused aggregate ----------------
// out[n,:] = relu( (sum_e bf16(xt[col[e],:])) / deg[n] ) + xt[n,:]
// One 64-lane wave per node. uint4 (16B) gathers, lanes split into 4 quarters
// of 16: quarter q / sublane h loads features 8h..8h+7 of edge 4t+q ->
// 1024 B and FOUR edges per VMEM instruction. Flight of 8 instrs = 32 edges
// (one drain for the average node). Final merge: shfl_down 32 then 16;
// lanes 0-15 hold the 128-feature row. Normal (cached) loads — xtb is
// L2-resident by design; nt hint regressed (round 8).
__global__ void gcn_aggregate(const uint4* __restrict__ xtb4, const float* xt,
                              const unsigned short* __restrict__ colell,
                              const int* __restrict__ deg,
                              float* out, int N) {
    const int gid  = blockIdx.x * blockDim.x + threadIdx.x;
    const int node = gid >> 6;
    const int lane = threadIdx.x & 63;
    if (node >= N) return;
    const int h  = lane & 15;       // feature octet: features 8h..8h+7
    const int qt = lane >> 4;       // 0..3: edge substream

    const uint4* __restrict__ xl = xtb4 + h;
    const unsigned short* __restrict__ crow = colell + (node << 7);
    const int cnt = deg[node];      // wave-uniform

    float a0 = 0.f, a1 = 0.f, a2 = 0.f, a3 = 0.f;
    float a4 = 0.f, a5 = 0.f, a6 = 0.f, a7 = 0.f;

#define ACC_U4(u)                                     \
    do {                                              \
        a0 += __uint_as_float((u).x << 16);           \
        a1 += __uint_as_float((u).x & 0xffff0000u);   \
        a2 += __uint_as_float((u).y << 16);           \
        a3 += __uint_as_float((u).y & 0xffff0000u);   \
        a4 += __uint_as_float((u).z << 16);           \
        a5 += __uint_as_float((u).z & 0xffff0000u);   \
        a6 += __uint_as_float((u).w << 16);           \
        a7 += __uint_as_float((u).w & 0xffff0000u);   \
    } while (0)

    for (int base = 0; base < cnt; base += 64) {
        const int rem = cnt - base;
        const int c = rem < 64 ? rem : 64;
        const int myidx = (lane < c) ? (int)crow[base + lane] : 0;  // coalesced ushort
        const int quads = c >> 2;
        int t = 0;
        for (; t + 8 <= quads; t += 8) {    // flight of 8 instrs = 32 edges
            uint4 u[8];
#pragma unroll
            for (int q = 0; q < 8; ++q) {
                int s = __shfl(myidx, 4 * (t + q) + qt, 64);
                u[q] = xl[s << 4];
            }
#pragma unroll
            for (int q = 0; q < 8; ++q) ACC_U4(u[q]);
        }
        for (; t + 2 <= quads; t += 2) {    // flight of 2 = 8 edges
            uint4 u0, u1;
            int s0 = __shfl(myidx, 4 * t + qt, 64);
            int s1 = __shfl(myidx, 4 * t + 4 + qt, 64);
            u0 = xl[s0 << 4];
            u1 = xl[s1 << 4];
            ACC_U4(u0);
            ACC_U4(u1);
        }
        for (; t < quads; ++t) {
            int s = __shfl(myidx, 4 * t + qt, 64);
            uint4 u = xl[s << 4];
            ACC_U4(u);
        }
        const int r = c & 3;
        if (r) {                            // tail: quarter qt handles edge 4*quads+qt
            int eidx = 4 * quads + qt;      // < 64 always (r>0 => quads<16)
            int s = __shfl(myidx, eidx, 64);
            if (eidx < c) {
                uint4 u = xl[s << 4];
                ACC_U4(u);
            }
        }
    }
#undef ACC_U4

    // merge the 4 edge substreams into lanes 0-15
    a0 += __shfl_down(a0, 32, 64); a1 += __shfl_down(a1, 32, 64);
    a2 += __shfl_down(a2, 32, 64); a3 += __shfl_down(a3, 32, 64);
    a4 += __shfl_down(a4, 32, 64); a5 += __shfl_down(a5, 32, 64);
    a6 += __shfl_down(a6, 32, 64); a7 += __shfl_down(a7, 32, 64);
    a0 += __shfl_down(a0, 16, 64); a1 += __shfl_down(a1, 16, 64);
    a2 += __shfl_down(a2, 16, 64); a3 += __shfl_down(a3, 16, 64);
    a4 += __shfl_down(a4, 16, 64); a5 += __shfl_down(a5, 16, 64);
    a6 += __shfl_down(a6, 16, 64); a7 += __shfl_down(a7, 16, 64);

    if (lane < 16) {
        const float di = (cnt > 0) ? (1.0f / (float)cnt) : 0.0f;
        float4 t0 = ((const float4*)xt)[node * 32 + h * 2];
        float4 t1 = ((const float4*)xt)[node * 32 + h * 2 + 1];
        float4 o0, o1;
        o0.x = fmaxf(a0 * di, 0.f) + t0.x;
        o0.y = fmaxf(a1 * di, 0.f) + t0.y;
        o0.z = fmaxf(a2 * di, 0.f) + t0.z;
        o0.w = fmaxf(a3 * di, 0.f) + t0.w;
        o1.x = fmaxf(a4 * di, 0.f) + t1.x;
        o1.y = fmaxf(a5 * di, 0.f) + t1.y;
        o1.z = fmaxf(a6 * di, 0.f) + t1.z;
        o1.w = fmaxf(a7 * di, 0.f) + t1.w;
        ((float4*)out)[node * 32 + h * 2]     = o0;
        ((float4*)out)[node * 32 + h * 2 + 1] = o1;
    }
}

extern "C" void kernel_launch(void* const* d_in, const int* in_sizes, int n_in,
                              void* d_out, int out_size, void* d_ws, size_t ws_size,
                              hipStream_t stream) {
    const float* x  = (const float*)d_in[0];
    const int*   ei = (const int*)d_in[1];      // [2, E] int32
    const float* W1 = (const float*)d_in[2];
    const float* b1 = (const float*)d_in[3];
    const float* W2 = (const float*)d_in[4];
    const float* b2 = (const float*)d_in[5];
    const float* W3 = (const float*)d_in[6];
    const float* b3 = (const float*)d_in[7];

    const int N  = in_sizes[0] / DD;     // 20000
    const int E  = in_sizes[1] / 2;      // 640000
    const int ND = N * DD;               // 2,560,000

    const int* src = ei;
    const int* dst = ei + E;

    const int NB = (N + 63) >> 6;        // 313 buckets
    const int PA = (E + AEPW - 1) / AEPW;    // 157 phase-A blocks
    const int GB = (N + MT - 1) / MT;        // 313 gemm blocks
    const int AB = (N + 3) / 4;              // aggregate blocks (4 waves/block)

    // workspace layout (256B-aligned offsets) — ~13.2 MB total
    char* ws = (char*)d_ws;
    size_t off = 0;
    auto alloc = [&](size_t bytes) {
        void* p = ws + off;
        off += (bytes + 255) & ~(size_t)255;
        return p;
    };
    int*            bucket_count = (int*)alloc((size_t)NB * sizeof(int));
    unsigned*       bstore       = (unsigned*)alloc((size_t)NB * ACAP * sizeof(unsigned));
    unsigned short* colell       = (unsigned short*)alloc((size_t)NB * 64 * ELLC * sizeof(unsigned short));
    int*            deg          = (int*)alloc((size_t)N * sizeof(int));
    unsigned*       xtb          = (unsigned*)alloc((size_t)(ND / 2) * sizeof(unsigned));

    float* xbuf = (float*)d_out;  // fp32 xt lives in d_out (in-place per layer)

    hipMemsetAsync(bucket_count, 0, (size_t)NB * sizeof(int), stream);
    // K1: Phase-A binning + layer-1 GEMM (x -> xbuf fp32 + xtb bf16)
    gemm1_plus_binA<<<PA + GB, 256, 0, stream>>>(x, W1, b1, xbuf, xtb, N,
                                                 src, dst, bucket_count, bstore, E, NB, PA);
    // K2: Phase-B ELL build (LDS atomics, local writes) + deg
    ell_build<<<NB, 256, 0, stream>>>(bstore, bucket_count, colell, deg, N);

    gcn_aggregate<<<AB, 256, 0, stream>>>((const uint4*)xtb, xbuf, colell, deg, xbuf, N);

    gemm_xwT<<<GB, 256, 0, stream>>>(xbuf, W2, b2, xbuf, xtb, N);
    gcn_aggregate<<<AB, 256, 0, stream>>>((const uint4*)xtb, xbuf, colell, deg, xbuf, N);

    gemm_xwT<<<GB, 256, 0, stream>>>(xbuf, W3, b3, xbuf, xtb, N);
    gcn_aggregate<<<AB, 256, 0, stream>>>((const uint4*)xtb, xbuf, colell, deg, xbuf, N);
}